// Round 17
// baseline (205.001 us; speedup 1.0000x reference)
//
#include <hip/hip_runtime.h>
#include <math.h>

#define BN 8
#define SN 2048
#define DN 512
#define UN 512
#define MN (BN*SN)   // 16384

typedef _Float16 f16;
typedef _Float16 f16x8 __attribute__((ext_vector_type(8)));
typedef _Float16 f16x4 __attribute__((ext_vector_type(4)));
typedef _Float16 f16x2 __attribute__((ext_vector_type(2)));
typedef float    f32x4 __attribute__((ext_vector_type(4)));

// 1/sqrt(512) * log2(e): scores computed directly in log2 domain
#define SCALE2 0.06376164464722629f
#define DEFER_THR2 11.541560327111708f   // 8 * log2(e): P bounded by e^8

#define CVT_PK(a, b) __builtin_bit_cast(f16x2, __builtin_amdgcn_cvt_pkrtz((a), (b)))

#define BAR_LGKM() do {                                         \
  asm volatile("s_waitcnt lgkmcnt(0)" ::: "memory");            \
  __builtin_amdgcn_s_barrier();                                 \
  __builtin_amdgcn_sched_barrier(0);                            \
} while (0)

__device__ __forceinline__ void gload_lds16(const f16* g, f16* l) {
  __builtin_amdgcn_global_load_lds(
      (const __attribute__((address_space(1))) unsigned int*)g,
      (__attribute__((address_space(3))) unsigned int*)l, 16, 0, 0);
}

// ---------------- fp32 -> fp16 convert of x ----------------
__global__ __launch_bounds__(256) void cvt_x_kernel(const float* __restrict__ x,
                                                    f16* __restrict__ x16) {
  int i = (blockIdx.x * 256 + threadIdx.x) * 4;
  float4 v = *(const float4*)(x + i);
  f16x4 o = { (f16)v.x, (f16)v.y, (f16)v.z, (f16)v.w };
  *(f16x4*)(x16 + i) = o;
}

// ------------- fp32 -> fp16 convert + transpose of W -------------
// Wt[widx][n][k] = W[k][n]; W_q scaled by (1/sqrt(units))*log2(e) so that
// QK^T scores are in log2 domain (softmax uses exp2 with no multiply).
__global__ __launch_bounds__(256) void cvt_w_kernel(const float* __restrict__ Wq,
                                                    const float* __restrict__ Wk,
                                                    const float* __restrict__ Wv,
                                                    f16* __restrict__ Wt) {
  const float* W = blockIdx.y == 0 ? Wq : (blockIdx.y == 1 ? Wk : Wv);
  const float s = blockIdx.y == 0 ? SCALE2 : 1.0f;
  f16* o = Wt + (size_t)blockIdx.y * DN * UN;
  int t = blockIdx.x * 256 + threadIdx.x;   // 0..65535
  int r  = t >> 7;          // k row 0..511
  int c4 = (t & 127) * 4;   // n col
  float4 v = *(const float4*)(W + (size_t)r * UN + c4);
  o[(size_t)(c4 + 0) * DN + r] = (f16)(v.x * s);
  o[(size_t)(c4 + 1) * DN + r] = (f16)(v.y * s);
  o[(size_t)(c4 + 2) * DN + r] = (f16)(v.z * s);
  o[(size_t)(c4 + 3) * DN + r] = (f16)(v.w * s);
}

// ---------------- QKV projection GEMM ----------------
__global__ __launch_bounds__(256) void qkv_gemm(const f16* __restrict__ x16,
                                                const f16* __restrict__ Wt,
                                                f16* __restrict__ Qh,
                                                f16* __restrict__ Kh,
                                                f16* __restrict__ Vt) {
  __shared__ __align__(16) f16 As[128 * 32];
  __shared__ __align__(16) f16 Bs[128 * 32];

  const int tid = threadIdx.x;
  const int w = tid >> 6, lane = tid & 63;
  const int l15 = lane & 15, lh = lane >> 4;
  const int m0 = blockIdx.x * 128;
  const int n0 = blockIdx.y * 128;
  const int widx = blockIdx.z;
  const f16* Wbase = Wt + (size_t)widx * DN * UN;

  const int wr = (w >> 1) * 64, wc = (w & 1) * 64;
  f32x4 acc[4][4] = {};

  for (int kk = 0; kk < 16; ++kk) {
    const int k0 = kk * 32;
#pragma unroll
    for (int q = 0; q < 2; ++q) {
      int j = q * 256 + tid;           // LDS 16B-chunk index
      int r = j >> 2, cs = j & 3;
      int c = cs ^ ((r >> 1) & 3);     // inverse swizzle on the SOURCE
      f16* abase = &As[(q * 256 + w * 64) * 8];
      f16* bbase = &Bs[(q * 256 + w * 64) * 8];
      gload_lds16(x16 + (size_t)(m0 + r) * DN + k0 + c * 8, abase);
      gload_lds16(Wbase + (size_t)(n0 + r) * DN + k0 + c * 8, bbase);
    }
    __syncthreads();

    f16x8 a[4], bfr[4];
#pragma unroll
    for (int m = 0; m < 4; ++m) {
      int row = wr + m * 16 + l15;
      int ch = lh ^ ((row >> 1) & 3);
      a[m] = *(const f16x8*)&As[row * 32 + ch * 8];
    }
#pragma unroll
    for (int n = 0; n < 4; ++n) {
      int row = wc + n * 16 + l15;
      int ch = lh ^ ((row >> 1) & 3);
      bfr[n] = *(const f16x8*)&Bs[row * 32 + ch * 8];
    }
#pragma unroll
    for (int m = 0; m < 4; ++m)
#pragma unroll
      for (int n = 0; n < 4; ++n)
        acc[m][n] = __builtin_amdgcn_mfma_f32_16x16x32_f16(a[m], bfr[n], acc[m][n], 0, 0, 0);
    __syncthreads();
  }

  if (widx == 2) {
#pragma unroll
    for (int m = 0; m < 4; ++m) {
      int g = m0 + wr + m * 16 + lh * 4;
      int bb = g >> 11;
      int ss = g & 2047;
#pragma unroll
      for (int n = 0; n < 4; ++n) {
        int u = n0 + wc + n * 16 + l15;
        f16x4 pv = { (f16)acc[m][n][0], (f16)acc[m][n][1],
                     (f16)acc[m][n][2], (f16)acc[m][n][3] };
        *(f16x4*)(Vt + ((size_t)bb * UN + u) * SN + ss) = pv;  // V^T[b][u][s]
      }
    }
  } else {
    f16* O = (widx == 0) ? Qh : Kh;
#pragma unroll
    for (int m = 0; m < 4; ++m)
#pragma unroll
      for (int n = 0; n < 4; ++n)
#pragma unroll
        for (int j = 0; j < 4; ++j)
          O[(size_t)(m0 + wr + m * 16 + lh * 4 + j) * UN + (n0 + wc + n * 16 + l15)] =
              (f16)acc[m][n][j];
  }
}

// ---------------- fused flash attention v17 = v13 + micro-opts ----------------
// 2-barrier deep pipeline (frozen structure); scores in log2 domain (exp2
// direct, no per-exp multiply); Ps written as 2x b64; redundant final
// vmcnt(0) removed (compiler tracks vreg deps into epilogue).
__global__ __launch_bounds__(512, 2) void attn_kernel(const f16* __restrict__ Qh,
                                                      const f16* __restrict__ Kh,
                                                      const f16* __restrict__ Vt,
                                                      float* __restrict__ out) {
  __shared__ __align__(16) f16 Ks[2][64 * 512];  // 128 KB dbuf, chunk-swz c^(r&7)
  __shared__ __align__(16) f16 Ps[2][64 * 72];   // 18 KB dbuf [q][kv+pad8]
  __shared__ float redm[2][4][16];               // [cs][rb][q-within]
  __shared__ float redl[2][4][16];

  const int tid = threadIdx.x;
  const int w = tid >> 6, lane = tid & 63;
  const int l15 = lane & 15, lh = lane >> 4;
  const int bid = blockIdx.x;
  const int b = bid & 7;              // XCD pin: batch per XCD (K+V = 4MB = L2)
  const int q0 = (bid >> 3) * 64;
  const int rb = w >> 1;              // QK q-group (16 rows)
  const int cs = w & 1;               // QK kv-half (32 cols)

  const f16* Kbat = Kh + (size_t)b * SN * DN;
  const f16* Vbat = Vt + (size_t)b * UN * SN;

  // Q B-frags: col q = q0+rb*16+l15, k = kc*32+lh*8
  const f16* Qbase = Qh + (size_t)(b * SN + q0 + rb * 16 + l15) * DN;
  f16x8 qf[16];
#pragma unroll
  for (int kc = 0; kc < 16; ++kc)
    qf[kc] = *(const f16x8*)(Qbase + kc * 32 + lh * 8);

  // acc: O^T[u = w*64+ut*16+lh*4+j][q = qt*16+l15]
  f32x4 acc[4][4] = {};
  float mj[4] = { -1e30f, -1e30f, -1e30f, -1e30f };   // per-lane q = qt*16+l15
  float rsA[4] = { 1.f, 1.f, 1.f, 1.f };              // pending acc rescale
  bool pend = false;
  float mrow = -1e30f, lrow = 0.f;                    // QK-role row state, q = l15

  // V A-frag base: lane (l15,lh) reads V^T[w*64+ut*16+l15][kv + ks*32 + lh*8]
  const f16* vbase = Vbat + (size_t)(w * 64 + l15) * SN + lh * 8;
  f16x8 vreg[4][2];

  // ---- prologue: K(0) DMA -> Ks[0]
#pragma unroll
  for (int q = 0; q < 8; ++q) {
    int r = w * 8 + q;
    gload_lds16(Kbat + (size_t)r * DN + (lane ^ (r & 7)) * 8, &Ks[0][r * 512]);
  }
  asm volatile("s_waitcnt vmcnt(0)" ::: "memory");
  __builtin_amdgcn_s_barrier();
  __builtin_amdgcn_sched_barrier(0);

  const int kswz = l15 & 7;

  for (int t = 0; t < 32; ++t) {
    const int cur = t & 1;
    const int kv0 = t * 64;

    // (a) K-DMA(t+1) into other buffer — in flight until bar2's vmcnt(8)
    if (t < 31) {
#pragma unroll
      for (int q = 0; q < 8; ++q) {
        int r = w * 8 + q;
        gload_lds16(Kbat + (size_t)(kv0 + 64 + r) * DN + (lane ^ (r & 7)) * 8,
                    &Ks[cur ^ 1][r * 512]);
      }
    }

    // (b) QK^T(t) swapped: sc col=l15=q, row=lh*4+j=kv (log2-domain scores)
    f32x4 sc0 = {}, sc1 = {};
    const int r0 = cs * 32 + l15;
    __builtin_amdgcn_s_setprio(1);
#pragma unroll
    for (int kc = 0; kc < 16; ++kc) {
      int ch = ((kc * 4 + lh) ^ kswz) * 8;
      f16x8 k0 = *(const f16x8*)&Ks[cur][r0 * 512 + ch];
      f16x8 k1 = *(const f16x8*)&Ks[cur][(r0 + 16) * 512 + ch];
      sc0 = __builtin_amdgcn_mfma_f32_16x16x32_f16(k0, qf[kc], sc0, 0, 0, 0);
      sc1 = __builtin_amdgcn_mfma_f32_16x16x32_f16(k1, qf[kc], sc1, 0, 0, 0);
    }
    __builtin_amdgcn_s_setprio(0);

    // (c) per-row (q=l15) max over this wave's 32 kv
    float pm = fmaxf(fmaxf(fmaxf(sc0[0], sc0[1]), fmaxf(sc0[2], sc0[3])),
                     fmaxf(fmaxf(sc1[0], sc1[1]), fmaxf(sc1[2], sc1[3])));
    pm = fmaxf(pm, __shfl_xor(pm, 16, 64));
    pm = fmaxf(pm, __shfl_xor(pm, 32, 64));
    if (lh == 0) redm[cs][rb][l15] = pm;
    BAR_LGKM();                       // bar1: redm(t) visible

    // (e) PV(t-1): apply pending rescale, then vreg(V(t-1)) x Ps[prev]
    if (t > 0) {
      if (pend) {
#pragma unroll
        for (int qt = 0; qt < 4; ++qt)
#pragma unroll
          for (int ut = 0; ut < 4; ++ut) {
            acc[ut][qt][0] *= rsA[qt]; acc[ut][qt][1] *= rsA[qt];
            acc[ut][qt][2] *= rsA[qt]; acc[ut][qt][3] *= rsA[qt];
          }
        pend = false;
      }
      __builtin_amdgcn_s_setprio(1);
#pragma unroll
      for (int ks = 0; ks < 2; ++ks) {
#pragma unroll
        for (int qt = 0; qt < 4; ++qt) {
          f16x8 pf = *(const f16x8*)&Ps[cur ^ 1][(qt * 16 + l15) * 72 + ks * 32 + lh * 8];
#pragma unroll
          for (int ut = 0; ut < 4; ++ut)
            acc[ut][qt] = __builtin_amdgcn_mfma_f32_16x16x32_f16(vreg[ut][ks], pf,
                                                                 acc[ut][qt], 0, 0, 0);
        }
      }
      __builtin_amdgcn_s_setprio(0);
    }

    // (f) vreg <- V(t) A-frags (consumed by PV(t) next iter / epilogue)
#pragma unroll
    for (int ut = 0; ut < 4; ++ut)
#pragma unroll
      for (int ks = 0; ks < 2; ++ks)
        vreg[ut][ks] = *(const f16x8*)(vbase + (size_t)(ut * 16) * SN + kv0 + ks * 32);

    // (g) softmax(t): merged max (defer), P = exp2 (log2 domain), Ps[cur], lrow
    float mn[4];
    bool need = false;
#pragma unroll
    for (int qt = 0; qt < 4; ++qt) {
      mn[qt] = fmaxf(mj[qt], fmaxf(redm[0][qt][l15], redm[1][qt][l15]));
      need = need || (mn[qt] > mj[qt] + DEFER_THR2);
    }
    if (__any(need)) {
#pragma unroll
      for (int qt = 0; qt < 4; ++qt) {
        rsA[qt] = exp2f(mj[qt] - mn[qt]);
        mj[qt] = mn[qt];
      }
      pend = true;
      float rsr = exp2f(mrow - mj[rb]);
      mrow = mj[rb];
      lrow *= rsr;
    }

    float p[8];
#pragma unroll
    for (int j = 0; j < 4; ++j) {
      p[j]     = exp2f(sc0[j] - mrow);
      p[4 + j] = exp2f(sc1[j] - mrow);
    }
    float ts = (p[0] + p[1]) + (p[2] + p[3]) + (p[4] + p[5]) + (p[6] + p[7]);
    ts += __shfl_xor(ts, 16, 64);
    ts += __shfl_xor(ts, 32, 64);
    lrow += ts;

    const int pbase = (rb * 16 + l15) * 72 + cs * 32 + lh * 4;
    {
      f16x2 a0 = CVT_PK(p[0], p[1]), a1 = CVT_PK(p[2], p[3]);
      f16x2 b0 = CVT_PK(p[4], p[5]), b1 = CVT_PK(p[6], p[7]);
      f16x4 w0 = { a0[0], a0[1], a1[0], a1[1] };
      f16x4 w1 = { b0[0], b0[1], b1[0], b1[1] };
      *(f16x4*)&Ps[cur][pbase +  0] = w0;
      *(f16x4*)&Ps[cur][pbase + 16] = w1;
    }

    // (h) bar2: Ps(t) visible; K-DMA(t+1) drained; vreg(t) stays in flight
    if (t < 31) {
      asm volatile("s_waitcnt vmcnt(8) lgkmcnt(0)" ::: "memory");
    } else {
      asm volatile("s_waitcnt lgkmcnt(0)" ::: "memory");
    }
    __builtin_amdgcn_s_barrier();
    __builtin_amdgcn_sched_barrier(0);
  }

  // ---- epilogue: pending rescale + final PV(31) from Ps[1], vreg V(31)
  if (pend) {
#pragma unroll
    for (int qt = 0; qt < 4; ++qt)
#pragma unroll
      for (int ut = 0; ut < 4; ++ut) {
        acc[ut][qt][0] *= rsA[qt]; acc[ut][qt][1] *= rsA[qt];
        acc[ut][qt][2] *= rsA[qt]; acc[ut][qt][3] *= rsA[qt];
      }
  }
#pragma unroll
  for (int ks = 0; ks < 2; ++ks) {
#pragma unroll
    for (int qt = 0; qt < 4; ++qt) {
      f16x8 pf = *(const f16x8*)&Ps[1][(qt * 16 + l15) * 72 + ks * 32 + lh * 8];
#pragma unroll
      for (int ut = 0; ut < 4; ++ut)
        acc[ut][qt] = __builtin_amdgcn_mfma_f32_16x16x32_f16(vreg[ut][ks], pf,
                                                             acc[ut][qt], 0, 0, 0);
    }
  }

  // merge lrow across cs, normalize, write O
  if (lh == 0) redl[cs][rb][l15] = lrow;
  __syncthreads();
#pragma unroll
  for (int qt = 0; qt < 4; ++qt) {
    float linv = 1.0f / (redl[0][qt][l15] + redl[1][qt][l15]);
    float* orow = out + (size_t)(b * SN + q0 + qt * 16 + l15) * UN + w * 64 + lh * 4;
#pragma unroll
    for (int ut = 0; ut < 4; ++ut) {
      f32x4 o = acc[ut][qt];
      o[0] *= linv; o[1] *= linv; o[2] *= linv; o[3] *= linv;
      *(f32x4*)(orow + ut * 16) = o;
    }
  }
}

extern "C" void kernel_launch(void* const* d_in, const int* in_sizes, int n_in,
                              void* d_out, int out_size, void* d_ws, size_t ws_size,
                              hipStream_t stream) {
  const float* x  = (const float*)d_in[0];
  const float* Wq = (const float*)d_in[1];
  const float* Wk = (const float*)d_in[2];
  const float* Wv = (const float*)d_in[3];
  float* out = (float*)d_out;

  f16* x16 = (f16*)d_ws;
  f16* Wt  = x16 + (size_t)MN * DN;
  f16* Qh  = Wt + (size_t)3 * DN * UN;
  f16* Kh  = Qh + (size_t)MN * UN;
  f16* Vt  = Kh + (size_t)MN * UN;

  cvt_x_kernel<<<dim3(MN * DN / 1024), 256, 0, stream>>>(x, x16);
  cvt_w_kernel<<<dim3(256, 3), 256, 0, stream>>>(Wq, Wk, Wv, Wt);
  qkv_gemm<<<dim3(128, 4, 3), 256, 0, stream>>>(x16, Wt, Qh, Kh, Vt);
  attn_kernel<<<256, 512, 0, stream>>>(Qh, Kh, Vt, out);
}

// Round 18
// 193.458 us; speedup vs baseline: 1.0597x; 1.0597x over previous
//
#include <hip/hip_runtime.h>
#include <math.h>

#define BN 8
#define SN 2048
#define DN 512
#define UN 512
#define MN (BN*SN)   // 16384

typedef _Float16 f16;
typedef _Float16 f16x8 __attribute__((ext_vector_type(8)));
typedef _Float16 f16x4 __attribute__((ext_vector_type(4)));
typedef _Float16 f16x2 __attribute__((ext_vector_type(2)));
typedef float    f32x4 __attribute__((ext_vector_type(4)));

#define SCALE 0.044194173824159216f   // 1/sqrt(512), folded into W_q at convert
#define LOG2E 1.4426950408889634f
#define DEFER_THR 8.0f

#define CVT_PK(a, b) __builtin_bit_cast(f16x2, __builtin_amdgcn_cvt_pkrtz((a), (b)))

#define BAR_LGKM() do {                                         \
  asm volatile("s_waitcnt lgkmcnt(0)" ::: "memory");            \
  __builtin_amdgcn_s_barrier();                                 \
  __builtin_amdgcn_sched_barrier(0);                            \
} while (0)

__device__ __forceinline__ void gload_lds16(const f16* g, f16* l) {
  __builtin_amdgcn_global_load_lds(
      (const __attribute__((address_space(1))) unsigned int*)g,
      (__attribute__((address_space(3))) unsigned int*)l, 16, 0, 0);
}

// ---------------- fp32 -> fp16 convert of x ----------------
__global__ __launch_bounds__(256) void cvt_x_kernel(const float* __restrict__ x,
                                                    f16* __restrict__ x16) {
  int i = (blockIdx.x * 256 + threadIdx.x) * 4;
  float4 v = *(const float4*)(x + i);
  f16x4 o = { (f16)v.x, (f16)v.y, (f16)v.z, (f16)v.w };
  *(f16x4*)(x16 + i) = o;
}

// ------------- fp32 -> fp16 convert + transpose of W -------------
__global__ __launch_bounds__(256) void cvt_w_kernel(const float* __restrict__ Wq,
                                                    const float* __restrict__ Wk,
                                                    const float* __restrict__ Wv,
                                                    f16* __restrict__ Wt) {
  const float* W = blockIdx.y == 0 ? Wq : (blockIdx.y == 1 ? Wk : Wv);
  const float s = blockIdx.y == 0 ? SCALE : 1.0f;
  f16* o = Wt + (size_t)blockIdx.y * DN * UN;
  int t = blockIdx.x * 256 + threadIdx.x;   // 0..65535
  int r  = t >> 7;          // k row 0..511
  int c4 = (t & 127) * 4;   // n col
  float4 v = *(const float4*)(W + (size_t)r * UN + c4);
  o[(size_t)(c4 + 0) * DN + r] = (f16)(v.x * s);
  o[(size_t)(c4 + 1) * DN + r] = (f16)(v.y * s);
  o[(size_t)(c4 + 2) * DN + r] = (f16)(v.z * s);
  o[(size_t)(c4 + 3) * DN + r] = (f16)(v.w * s);
}

// ---------------- QKV projection GEMM ----------------
__global__ __launch_bounds__(256) void qkv_gemm(const f16* __restrict__ x16,
                                                const f16* __restrict__ Wt,
                                                f16* __restrict__ Qh,
                                                f16* __restrict__ Kh,
                                                f16* __restrict__ Vt) {
  __shared__ __align__(16) f16 As[128 * 32];
  __shared__ __align__(16) f16 Bs[128 * 32];

  const int tid = threadIdx.x;
  const int w = tid >> 6, lane = tid & 63;
  const int l15 = lane & 15, lh = lane >> 4;
  const int m0 = blockIdx.x * 128;
  const int n0 = blockIdx.y * 128;
  const int widx = blockIdx.z;
  const f16* Wbase = Wt + (size_t)widx * DN * UN;

  const int wr = (w >> 1) * 64, wc = (w & 1) * 64;
  f32x4 acc[4][4] = {};

  for (int kk = 0; kk < 16; ++kk) {
    const int k0 = kk * 32;
#pragma unroll
    for (int q = 0; q < 2; ++q) {
      int j = q * 256 + tid;           // LDS 16B-chunk index
      int r = j >> 2, cs = j & 3;
      int c = cs ^ ((r >> 1) & 3);     // inverse swizzle on the SOURCE
      f16* abase = &As[(q * 256 + w * 64) * 8];
      f16* bbase = &Bs[(q * 256 + w * 64) * 8];
      gload_lds16(x16 + (size_t)(m0 + r) * DN + k0 + c * 8, abase);
      gload_lds16(Wbase + (size_t)(n0 + r) * DN + k0 + c * 8, bbase);
    }
    __syncthreads();

    f16x8 a[4], bfr[4];
#pragma unroll
    for (int m = 0; m < 4; ++m) {
      int row = wr + m * 16 + l15;
      int ch = lh ^ ((row >> 1) & 3);
      a[m] = *(const f16x8*)&As[row * 32 + ch * 8];
    }
#pragma unroll
    for (int n = 0; n < 4; ++n) {
      int row = wc + n * 16 + l15;
      int ch = lh ^ ((row >> 1) & 3);
      bfr[n] = *(const f16x8*)&Bs[row * 32 + ch * 8];
    }
#pragma unroll
    for (int m = 0; m < 4; ++m)
#pragma unroll
      for (int n = 0; n < 4; ++n)
        acc[m][n] = __builtin_amdgcn_mfma_f32_16x16x32_f16(a[m], bfr[n], acc[m][n], 0, 0, 0);
    __syncthreads();
  }

  if (widx == 2) {
#pragma unroll
    for (int m = 0; m < 4; ++m) {
      int g = m0 + wr + m * 16 + lh * 4;
      int bb = g >> 11;
      int ss = g & 2047;
#pragma unroll
      for (int n = 0; n < 4; ++n) {
        int u = n0 + wc + n * 16 + l15;
        f16x4 pv = { (f16)acc[m][n][0], (f16)acc[m][n][1],
                     (f16)acc[m][n][2], (f16)acc[m][n][3] };
        *(f16x4*)(Vt + ((size_t)bb * UN + u) * SN + ss) = pv;  // V^T[b][u][s]
      }
    }
  } else {
    f16* O = (widx == 0) ? Qh : Kh;
#pragma unroll
    for (int m = 0; m < 4; ++m)
#pragma unroll
      for (int n = 0; n < 4; ++n)
#pragma unroll
        for (int j = 0; j < 4; ++j)
          O[(size_t)(m0 + wr + m * 16 + lh * 4 + j) * UN + (n0 + wc + n * 16 + l15)] =
              (f16)acc[m][n][j];
  }
}

// ---------------- fused flash attention v13 (best verified) ----------------
// 2-barrier deep pipeline: Ks+Ps double-buffered; K-DMA(t+1) issued at iter
// top (full-iter flight); PV(t-1) after bar1 fills the bubble; acc rescale
// deferred-applied just before each PV. Counted vmcnt(8) at bar2.
// QBLK=64, KVBLK=64, grid 256 (1 blk/CU lockstep, XCD-pinned batch), 8 waves.
__global__ __launch_bounds__(512, 2) void attn_kernel(const f16* __restrict__ Qh,
                                                      const f16* __restrict__ Kh,
                                                      const f16* __restrict__ Vt,
                                                      float* __restrict__ out) {
  __shared__ __align__(16) f16 Ks[2][64 * 512];  // 128 KB dbuf, chunk-swz c^(r&7)
  __shared__ __align__(16) f16 Ps[2][64 * 72];   // 18 KB dbuf [q][kv+pad8]
  __shared__ float redm[2][4][16];               // [cs][rb][q-within]
  __shared__ float redl[2][4][16];

  const int tid = threadIdx.x;
  const int w = tid >> 6, lane = tid & 63;
  const int l15 = lane & 15, lh = lane >> 4;
  const int bid = blockIdx.x;
  const int b = bid & 7;              // XCD pin: batch per XCD (K+V = 4MB = L2)
  const int q0 = (bid >> 3) * 64;
  const int rb = w >> 1;              // QK q-group (16 rows)
  const int cs = w & 1;               // QK kv-half (32 cols)

  const f16* Kbat = Kh + (size_t)b * SN * DN;
  const f16* Vbat = Vt + (size_t)b * UN * SN;

  // Q B-frags: col q = q0+rb*16+l15, k = kc*32+lh*8
  const f16* Qbase = Qh + (size_t)(b * SN + q0 + rb * 16 + l15) * DN;
  f16x8 qf[16];
#pragma unroll
  for (int kc = 0; kc < 16; ++kc)
    qf[kc] = *(const f16x8*)(Qbase + kc * 32 + lh * 8);

  // acc: O^T[u = w*64+ut*16+lh*4+j][q = qt*16+l15]
  f32x4 acc[4][4] = {};
  float mj[4] = { -1e30f, -1e30f, -1e30f, -1e30f };   // per-lane q = qt*16+l15
  float rsA[4] = { 1.f, 1.f, 1.f, 1.f };              // pending acc rescale
  bool pend = false;
  float mrow = -1e30f, lrow = 0.f;                    // QK-role row state, q = l15

  // V A-frag base: lane (l15,lh) reads V^T[w*64+ut*16+l15][kv + ks*32 + lh*8]
  const f16* vbase = Vbat + (size_t)(w * 64 + l15) * SN + lh * 8;
  f16x8 vreg[4][2];

  // ---- prologue: K(0) DMA -> Ks[0]
#pragma unroll
  for (int q = 0; q < 8; ++q) {
    int r = w * 8 + q;
    gload_lds16(Kbat + (size_t)r * DN + (lane ^ (r & 7)) * 8, &Ks[0][r * 512]);
  }
  asm volatile("s_waitcnt vmcnt(0)" ::: "memory");
  __builtin_amdgcn_s_barrier();
  __builtin_amdgcn_sched_barrier(0);

  const int kswz = l15 & 7;

  for (int t = 0; t < 32; ++t) {
    const int cur = t & 1;
    const int kv0 = t * 64;

    // (a) K-DMA(t+1) into other buffer — in flight until bar2's vmcnt(8)
    if (t < 31) {
#pragma unroll
      for (int q = 0; q < 8; ++q) {
        int r = w * 8 + q;
        gload_lds16(Kbat + (size_t)(kv0 + 64 + r) * DN + (lane ^ (r & 7)) * 8,
                    &Ks[cur ^ 1][r * 512]);
      }
    }

    // (b) QK^T(t) swapped: sc col=l15=q, row=lh*4+j=kv
    f32x4 sc0 = {}, sc1 = {};
    const int r0 = cs * 32 + l15;
    __builtin_amdgcn_s_setprio(1);
#pragma unroll
    for (int kc = 0; kc < 16; ++kc) {
      int ch = ((kc * 4 + lh) ^ kswz) * 8;
      f16x8 k0 = *(const f16x8*)&Ks[cur][r0 * 512 + ch];
      f16x8 k1 = *(const f16x8*)&Ks[cur][(r0 + 16) * 512 + ch];
      sc0 = __builtin_amdgcn_mfma_f32_16x16x32_f16(k0, qf[kc], sc0, 0, 0, 0);
      sc1 = __builtin_amdgcn_mfma_f32_16x16x32_f16(k1, qf[kc], sc1, 0, 0, 0);
    }
    __builtin_amdgcn_s_setprio(0);

    // (c) per-row (q=l15) max over this wave's 32 kv
    float pm = fmaxf(fmaxf(fmaxf(sc0[0], sc0[1]), fmaxf(sc0[2], sc0[3])),
                     fmaxf(fmaxf(sc1[0], sc1[1]), fmaxf(sc1[2], sc1[3])));
    pm = fmaxf(pm, __shfl_xor(pm, 16, 64));
    pm = fmaxf(pm, __shfl_xor(pm, 32, 64));
    if (lh == 0) redm[cs][rb][l15] = pm;
    BAR_LGKM();                       // bar1: redm(t) visible

    // (e) PV(t-1): apply pending rescale, then vreg(V(t-1)) x Ps[prev]
    if (t > 0) {
      if (pend) {
#pragma unroll
        for (int qt = 0; qt < 4; ++qt)
#pragma unroll
          for (int ut = 0; ut < 4; ++ut) {
            acc[ut][qt][0] *= rsA[qt]; acc[ut][qt][1] *= rsA[qt];
            acc[ut][qt][2] *= rsA[qt]; acc[ut][qt][3] *= rsA[qt];
          }
        pend = false;
      }
      __builtin_amdgcn_s_setprio(1);
#pragma unroll
      for (int ks = 0; ks < 2; ++ks) {
#pragma unroll
        for (int qt = 0; qt < 4; ++qt) {
          f16x8 pf = *(const f16x8*)&Ps[cur ^ 1][(qt * 16 + l15) * 72 + ks * 32 + lh * 8];
#pragma unroll
          for (int ut = 0; ut < 4; ++ut)
            acc[ut][qt] = __builtin_amdgcn_mfma_f32_16x16x32_f16(vreg[ut][ks], pf,
                                                                 acc[ut][qt], 0, 0, 0);
        }
      }
      __builtin_amdgcn_s_setprio(0);
    }

    // (f) vreg <- V(t) A-frags (consumed by PV(t) next iter / epilogue)
#pragma unroll
    for (int ut = 0; ut < 4; ++ut)
#pragma unroll
      for (int ks = 0; ks < 2; ++ks)
        vreg[ut][ks] = *(const f16x8*)(vbase + (size_t)(ut * 16) * SN + kv0 + ks * 32);

    // (g) softmax(t): merged max (defer), P = exp, Ps[cur] write, lrow
    float mn[4];
    bool need = false;
#pragma unroll
    for (int qt = 0; qt < 4; ++qt) {
      mn[qt] = fmaxf(mj[qt], fmaxf(redm[0][qt][l15], redm[1][qt][l15]));
      need = need || (mn[qt] > mj[qt] + DEFER_THR);
    }
    if (__any(need)) {
#pragma unroll
      for (int qt = 0; qt < 4; ++qt) {
        rsA[qt] = exp2f((mj[qt] - mn[qt]) * LOG2E);
        mj[qt] = mn[qt];
      }
      pend = true;
      float rsr = exp2f((mrow - mj[rb]) * LOG2E);
      mrow = mj[rb];
      lrow *= rsr;
    }

    float p[8];
#pragma unroll
    for (int j = 0; j < 4; ++j) {
      p[j]     = exp2f((sc0[j] - mrow) * LOG2E);
      p[4 + j] = exp2f((sc1[j] - mrow) * LOG2E);
    }
    float ts = (p[0] + p[1]) + (p[2] + p[3]) + (p[4] + p[5]) + (p[6] + p[7]);
    ts += __shfl_xor(ts, 16, 64);
    ts += __shfl_xor(ts, 32, 64);
    lrow += ts;

    const int pbase = (rb * 16 + l15) * 72 + cs * 32 + lh * 4;
    *(f16x2*)&Ps[cur][pbase +  0] = CVT_PK(p[0], p[1]);
    *(f16x2*)&Ps[cur][pbase +  2] = CVT_PK(p[2], p[3]);
    *(f16x2*)&Ps[cur][pbase + 16] = CVT_PK(p[4], p[5]);
    *(f16x2*)&Ps[cur][pbase + 18] = CVT_PK(p[6], p[7]);

    // (h) bar2: Ps(t) visible; K-DMA(t+1) drained; vreg(t) stays in flight
    asm volatile("s_waitcnt vmcnt(8) lgkmcnt(0)" ::: "memory");
    __builtin_amdgcn_s_barrier();
    __builtin_amdgcn_sched_barrier(0);
  }

  // ---- epilogue: pending rescale + final PV(31) from Ps[1], vreg V(31)
  if (pend) {
#pragma unroll
    for (int qt = 0; qt < 4; ++qt)
#pragma unroll
      for (int ut = 0; ut < 4; ++ut) {
        acc[ut][qt][0] *= rsA[qt]; acc[ut][qt][1] *= rsA[qt];
        acc[ut][qt][2] *= rsA[qt]; acc[ut][qt][3] *= rsA[qt];
      }
  }
#pragma unroll
  for (int ks = 0; ks < 2; ++ks) {
#pragma unroll
    for (int qt = 0; qt < 4; ++qt) {
      f16x8 pf = *(const f16x8*)&Ps[1][(qt * 16 + l15) * 72 + ks * 32 + lh * 8];
#pragma unroll
      for (int ut = 0; ut < 4; ++ut)
        acc[ut][qt] = __builtin_amdgcn_mfma_f32_16x16x32_f16(vreg[ut][ks], pf,
                                                             acc[ut][qt], 0, 0, 0);
    }
  }

  // merge lrow across cs, normalize, write O
  if (lh == 0) redl[cs][rb][l15] = lrow;
  __syncthreads();
#pragma unroll
  for (int qt = 0; qt < 4; ++qt) {
    float linv = 1.0f / (redl[0][qt][l15] + redl[1][qt][l15]);
    float* orow = out + (size_t)(b * SN + q0 + qt * 16 + l15) * UN + w * 64 + lh * 4;
#pragma unroll
    for (int ut = 0; ut < 4; ++ut) {
      f32x4 o = acc[ut][qt];
      o[0] *= linv; o[1] *= linv; o[2] *= linv; o[3] *= linv;
      *(f32x4*)(orow + ut * 16) = o;
    }
  }
}

extern "C" void kernel_launch(void* const* d_in, const int* in_sizes, int n_in,
                              void* d_out, int out_size, void* d_ws, size_t ws_size,
                              hipStream_t stream) {
  const float* x  = (const float*)d_in[0];
  const float* Wq = (const float*)d_in[1];
  const float* Wk = (const float*)d_in[2];
  const float* Wv = (const float*)d_in[3];
  float* out = (float*)d_out;

  f16* x16 = (f16*)d_ws;
  f16* Wt  = x16 + (size_t)MN * DN;
  f16* Qh  = Wt + (size_t)3 * DN * UN;
  f16* Kh  = Qh + (size_t)MN * UN;
  f16* Vt  = Kh + (size_t)MN * UN;

  cvt_x_kernel<<<dim3(MN * DN / 1024), 256, 0, stream>>>(x, x16);
  cvt_w_kernel<<<dim3(256, 3), 256, 0, stream>>>(Wq, Wk, Wv, Wt);
  qkv_gemm<<<dim3(128, 4, 3), 256, 0, stream>>>(x16, Wt, Qh, Kh, Vt);
  attn_kernel<<<256, 512, 0, stream>>>(Qh, Kh, Vt, out);
}